// Round 3
// baseline (6396.673 us; speedup 1.0000x reference)
//
#include <hip/hip_runtime.h>
#include <hip/hip_bf16.h>

// Problem constants (reference: B=2, T=2048, DIM=2048, HEADS=16, HEAD_DIM=128)
#define BB   2
#define TT   2048
#define CC   2048
#define HH   16
#define DD   128
#define N3   6144   // 3*DIM

typedef __attribute__((ext_vector_type(8))) short short8;
typedef __attribute__((ext_vector_type(4))) float f32x4;

__device__ inline unsigned short f2bf(float v) {
    __hip_bfloat16 h = __float2bfloat16(v);   // RNE rounding
    return *reinterpret_cast<unsigned short*>(&h);
}
__device__ inline float bf2f(unsigned short u) {
    return __uint_as_float(((unsigned int)u) << 16);
}

// ---------------------------------------------------------------------------
// Kernel 0a: fp32 -> bf16 elementwise (X -> Xb). n is float4 count.
// ---------------------------------------------------------------------------
__global__ __launch_bounds__(256) void cvt_f32_bf16(
    const float* __restrict__ in, unsigned short* __restrict__ out, int n4)
{
    for (int i = blockIdx.x * blockDim.x + threadIdx.x; i < n4;
         i += gridDim.x * blockDim.x) {
        float4 v = reinterpret_cast<const float4*>(in)[i];
        ushort4 o;
        o.x = f2bf(v.x); o.y = f2bf(v.y); o.z = f2bf(v.z); o.w = f2bf(v.w);
        reinterpret_cast<ushort4*>(out)[i] = o;
    }
}

// ---------------------------------------------------------------------------
// Kernel 0b: transpose + convert.  in fp32 [R][Cn]  ->  out bf16 [Cn][R].
// 64x64 tiles, 256 threads, LDS staging.
// ---------------------------------------------------------------------------
__global__ __launch_bounds__(256) void transpose_cvt(
    const float* __restrict__ in, unsigned short* __restrict__ out,
    int R, int Cn)
{
    __shared__ float tile[64][65];
    const int tid = threadIdx.x;
    const int n0  = blockIdx.x * 64;   // input col block
    const int r0  = blockIdx.y * 64;   // input row block

    #pragma unroll
    for (int it = 0; it < 4; ++it) {
        const int idx = tid + it * 256;      // 0..1023
        const int lr  = idx >> 4;            // 0..63
        const int lcq = idx & 15;            // float4 quad
        float4 v = *reinterpret_cast<const float4*>(
            &in[(size_t)(r0 + lr) * Cn + n0 + lcq * 4]);
        tile[lr][lcq * 4 + 0] = v.x;
        tile[lr][lcq * 4 + 1] = v.y;
        tile[lr][lcq * 4 + 2] = v.z;
        tile[lr][lcq * 4 + 3] = v.w;
    }
    __syncthreads();
    #pragma unroll
    for (int it = 0; it < 4; ++it) {
        const int idx = tid + it * 256;
        const int orow = idx >> 4;           // output row (n), 0..63
        const int ocq  = idx & 15;           // k quad
        ushort4 o;
        o.x = f2bf(tile[ocq * 4 + 0][orow]);
        o.y = f2bf(tile[ocq * 4 + 1][orow]);
        o.z = f2bf(tile[ocq * 4 + 2][orow]);
        o.w = f2bf(tile[ocq * 4 + 3][orow]);
        *reinterpret_cast<ushort4*>(&out[(size_t)(n0 + orow) * R + r0 + ocq * 4]) = o;
    }
}

// ---------------------------------------------------------------------------
// MFMA GEMM:  C[M][N] = A[M][K] * Bt[N][K]^T + bias, K=2048.
// A, Bt bf16 row-major (k-contiguous). 128x128 block tile, 4 waves (2x2),
// BK=64 per stage, reg-staged LDS (pitch 72 ushorts = 144B, 2-way = free).
// Fragment layouts (m89/m91-verified):
//   A/B: lane l holds 8 contiguous k at k=(l>>4)*8, row/col = l&15
//   C/D: col = l&15, row = (l>>4)*4 + reg
// MODE 0: qkv epilogue (scatter q->qws bf16, k/v->fp32 head layout)
// MODE 1: plain epilogue (out = acc + bias, fp32)
// ---------------------------------------------------------------------------
#define LDP 72   // LDS row pitch in ushorts (64 + 8 pad)

template<int MODE>
__global__ __launch_bounds__(256) void gemm_mfma_bf16(
    const unsigned short* __restrict__ A,    // [M][2048] bf16
    const unsigned short* __restrict__ Bt,   // [N][2048] bf16
    const float* __restrict__ bias,          // [N]
    unsigned short* __restrict__ qws,        // MODE 0
    float* __restrict__ kout,                // MODE 0
    float* __restrict__ vout,                // MODE 0
    float* __restrict__ Y)                   // MODE 1
{
    __shared__ unsigned short As[128 * LDP];
    __shared__ unsigned short Bs[128 * LDP];

    const int tid  = threadIdx.x;
    const int bm   = blockIdx.y * 128;
    const int bn   = blockIdx.x * 128;
    const int wave = tid >> 6;
    const int lane = tid & 63;
    const int wr   = wave >> 1;          // 0..1
    const int wc   = wave & 1;           // 0..1
    const int lrow = lane & 15;
    const int lk8  = (lane >> 4) * 8;    // k offset within 32

    // staging mapping: 1024 16B-chunks over [128][64] bf16
    const int srow = (tid * 4) >> 3;     // not used; see loop

    f32x4 acc[4][4];
    #pragma unroll
    for (int i = 0; i < 4; ++i)
        #pragma unroll
        for (int j = 0; j < 4; ++j)
            acc[i][j] = (f32x4){0.f, 0.f, 0.f, 0.f};

    for (int k0 = 0; k0 < 2048; k0 += 64) {
        uint4 ga[4], gb[4];
        #pragma unroll
        for (int it = 0; it < 4; ++it) {
            const int i   = tid + it * 256;   // 0..1023
            const int row = i >> 3;           // 0..127
            const int cq  = i & 7;            // 16B chunk within 64 k
            ga[it] = *reinterpret_cast<const uint4*>(
                &A[(size_t)(bm + row) * 2048 + k0 + cq * 8]);
            gb[it] = *reinterpret_cast<const uint4*>(
                &Bt[(size_t)(bn + row) * 2048 + k0 + cq * 8]);
        }
        __syncthreads();   // prev-iter LDS reads done
        #pragma unroll
        for (int it = 0; it < 4; ++it) {
            const int i   = tid + it * 256;
            const int row = i >> 3;
            const int cq  = i & 7;
            *reinterpret_cast<uint4*>(&As[row * LDP + cq * 8]) = ga[it];
            *reinterpret_cast<uint4*>(&Bs[row * LDP + cq * 8]) = gb[it];
        }
        __syncthreads();

        #pragma unroll
        for (int ks = 0; ks < 2; ++ks) {
            short8 af[4], bf[4];
            #pragma unroll
            for (int mi = 0; mi < 4; ++mi)
                af[mi] = *reinterpret_cast<const short8*>(
                    &As[(wr * 64 + mi * 16 + lrow) * LDP + ks * 32 + lk8]);
            #pragma unroll
            for (int ni = 0; ni < 4; ++ni)
                bf[ni] = *reinterpret_cast<const short8*>(
                    &Bs[(wc * 64 + ni * 16 + lrow) * LDP + ks * 32 + lk8]);
            #pragma unroll
            for (int mi = 0; mi < 4; ++mi)
                #pragma unroll
                for (int ni = 0; ni < 4; ++ni)
                    acc[mi][ni] = __builtin_amdgcn_mfma_f32_16x16x32_bf16(
                        af[mi], bf[ni], acc[mi][ni], 0, 0, 0);
        }
    }

    // epilogue
    const int rbase = (lane >> 4) * 4;
    #pragma unroll
    for (int mi = 0; mi < 4; ++mi) {
        #pragma unroll
        for (int ni = 0; ni < 4; ++ni) {
            #pragma unroll
            for (int r = 0; r < 4; ++r) {
                const int grow = bm + wr * 64 + mi * 16 + rbase + r;
                const int gcol = bn + wc * 64 + ni * 16 + lrow;
                const float val = acc[mi][ni][r] + bias[gcol];
                if (MODE == 0) {
                    const int b      = grow >> 11;
                    const int t      = grow & (TT - 1);
                    const int region = gcol >> 11;       // uniform per block
                    const int cc     = gcol & (CC - 1);
                    const int h      = cc >> 7;
                    const int d      = cc & (DD - 1);
                    const size_t idx = (((size_t)(b * HH + h)) * TT + t) * DD + d;
                    if (region == 0)      qws[idx]  = f2bf(val);
                    else if (region == 1) kout[idx] = val;
                    else                  vout[idx] = val;
                } else {
                    Y[(size_t)grow * CC + gcol] = val;
                }
            }
        }
    }
}

// ---------------------------------------------------------------------------
// Causal flash attention, fp32 compute. Q from bf16 ws; K/V fp32 (d_out);
// output written bf16 (feeds gemm3).
// Grid: (T/64, H, B). Block: 256 = 64 q-rows x 4 D-quarters.
// ---------------------------------------------------------------------------
__global__ __launch_bounds__(256) void attn_fwd(
    const unsigned short* __restrict__ qws,   // [B,H,T,D] bf16
    const float* __restrict__ kin,            // [B,H,T,D] fp32
    const float* __restrict__ vin,
    unsigned short* __restrict__ aout)        // [B,T,C] bf16
{
    __shared__ float Ks[64][128];
    __shared__ float Vs[64][128];

    const int qt  = blockIdx.x;
    const int h   = blockIdx.y;
    const int b   = blockIdx.z;
    const int tid = threadIdx.x;
    const int qi  = tid >> 2;
    const int sub = tid & 3;

    const float scale = 0.08838834764831845f;   // 1/sqrt(128)
    const size_t head_base = ((size_t)(b * HH + h)) * TT * DD;

    float qv[32];
    const unsigned short* qp = qws + head_base + (size_t)(qt * 64 + qi) * DD + sub * 32;
    #pragma unroll
    for (int j = 0; j < 8; ++j) {
        ushort4 u = *reinterpret_cast<const ushort4*>(qp + j * 4);
        qv[j * 4 + 0] = bf2f(u.x); qv[j * 4 + 1] = bf2f(u.y);
        qv[j * 4 + 2] = bf2f(u.z); qv[j * 4 + 3] = bf2f(u.w);
    }

    float m = -1e30f, l = 0.f;
    float o[32];
    #pragma unroll
    for (int j = 0; j < 32; ++j) o[j] = 0.f;

    const int ntiles = qt + 1;   // causal
    for (int kt = 0; kt < ntiles; ++kt) {
        __syncthreads();
        const float* kp = kin + head_base + (size_t)kt * 64 * DD;
        const float* vp = vin + head_base + (size_t)kt * 64 * DD;
        #pragma unroll
        for (int it = 0; it < 8; ++it) {
            const int i   = tid + it * 256;
            const int row = i >> 5;
            const int c4  = i & 31;
            *reinterpret_cast<float4*>(&Ks[row][c4 * 4]) =
                *reinterpret_cast<const float4*>(kp + row * DD + c4 * 4);
            *reinterpret_cast<float4*>(&Vs[row][c4 * 4]) =
                *reinterpret_cast<const float4*>(vp + row * DD + c4 * 4);
        }
        __syncthreads();

        float s[64];
        #pragma unroll
        for (int kj = 0; kj < 64; ++kj) {
            const float* krow = &Ks[kj][sub * 32];
            float p = 0.f;
            #pragma unroll
            for (int j = 0; j < 32; ++j) p = fmaf(qv[j], krow[j], p);
            p += __shfl_xor(p, 1);
            p += __shfl_xor(p, 2);
            s[kj] = p * scale;
        }
        if (kt == qt) {
            #pragma unroll
            for (int kj = 0; kj < 64; ++kj)
                if (kj > qi) s[kj] = -1e30f;
        }

        float mt = s[0];
        #pragma unroll
        for (int kj = 1; kj < 64; ++kj) mt = fmaxf(mt, s[kj]);
        const float mnew = fmaxf(m, mt);
        const float corr = __expf(m - mnew);
        l *= corr;
        #pragma unroll
        for (int j = 0; j < 32; ++j) o[j] *= corr;

        #pragma unroll
        for (int kj = 0; kj < 64; ++kj) {
            const float p = __expf(s[kj] - mnew);
            l += p;
            const float* vrow = &Vs[kj][sub * 32];
            #pragma unroll
            for (int j = 0; j < 32; ++j) o[j] = fmaf(p, vrow[j], o[j]);
        }
        m = mnew;
    }

    const float inv = 1.f / l;
    unsigned short* op = aout + ((size_t)(b * TT) + qt * 64 + qi) * CC + h * DD + sub * 32;
    #pragma unroll
    for (int j = 0; j < 8; ++j) {
        ushort4 u;
        u.x = f2bf(o[j*4+0] * inv); u.y = f2bf(o[j*4+1] * inv);
        u.z = f2bf(o[j*4+2] * inv); u.w = f2bf(o[j*4+3] * inv);
        *reinterpret_cast<ushort4*>(op + j * 4) = u;
    }
}

// ---------------------------------------------------------------------------
extern "C" void kernel_launch(void* const* d_in, const int* in_sizes, int n_in,
                              void* d_out, int out_size, void* d_ws, size_t ws_size,
                              hipStream_t stream) {
    const float* x    = (const float*)d_in[0];
    // d_in[1] = mask (bool tril) — causal mask hardcoded in attn_fwd
    const float* Wqkv = (const float*)d_in[2];
    const float* bqkv = (const float*)d_in[3];
    const float* Wout = (const float*)d_in[4];
    const float* bout = (const float*)d_in[5];

    float* out  = (float*)d_out;                       // [B,T,C] fp32
    float* kout = out + (size_t)BB * TT * CC;          // [B,H,T,D] fp32
    float* vout = kout + (size_t)BB * TT * CC;         // [B,H,T,D] fp32

    // workspace (bf16 regions, all 16B-aligned)
    unsigned short* Xb    = (unsigned short*)d_ws;                 // [4096][2048]
    unsigned short* Wqkvt = Xb    + (size_t)4096 * 2048;           // [6144][2048]
    unsigned short* Wott  = Wqkvt + (size_t)6144 * 2048;           // [2048][2048]
    unsigned short* qws   = Wott  + (size_t)2048 * 2048;           // [B,H,T,D]
    unsigned short* aoutb = qws   + (size_t)BB * TT * CC;          // [B,T,C]

    // 0) convert X to bf16; convert+transpose weights to bf16 [N][K]
    cvt_f32_bf16<<<2048, 256, 0, stream>>>(x, Xb, (int)((size_t)4096 * 2048 / 4));
    transpose_cvt<<<dim3(N3 / 64, CC / 64), 256, 0, stream>>>(Wqkv, Wqkvt, CC, N3);
    transpose_cvt<<<dim3(CC / 64, CC / 64), 256, 0, stream>>>(Wout, Wott, CC, CC);

    // 1) QKV projection (MFMA) + head scatter
    gemm_mfma_bf16<0><<<dim3(N3 / 128, (BB * TT) / 128), 256, 0, stream>>>(
        Xb, Wqkvt, bqkv, qws, kout, vout, nullptr);

    // 2) causal flash attention (fp32 compute)
    attn_fwd<<<dim3(TT / 64, HH, BB), 256, 0, stream>>>(qws, kout, vout, aoutb);

    // 3) output projection (MFMA)
    gemm_mfma_bf16<1><<<dim3(CC / 128, (BB * TT) / 128), 256, 0, stream>>>(
        aoutb, Wott, bout, nullptr, nullptr, nullptr, out);
}

// Round 7
// 961.733 us; speedup vs baseline: 6.6512x; 6.6512x over previous
//
#include <hip/hip_runtime.h>
#include <hip/hip_bf16.h>

// Problem constants (reference: B=2, T=2048, DIM=2048, HEADS=16, HEAD_DIM=128)
#define BB   2
#define TT   2048
#define CC   2048
#define HH   16
#define DD   128
#define N3   6144   // 3*DIM

typedef __attribute__((ext_vector_type(8))) short short8;
typedef __attribute__((ext_vector_type(4))) float f32x4;

__device__ inline unsigned short f2bf(float v) {
    __hip_bfloat16 h = __float2bfloat16(v);   // RNE rounding
    return *reinterpret_cast<unsigned short*>(&h);
}
__device__ inline float bf2f(unsigned short u) {
    return __uint_as_float(((unsigned int)u) << 16);
}

// ---------------------------------------------------------------------------
// Kernel 0a: fp32 -> bf16 elementwise (X -> Xb). n4 = float4 count.
// ---------------------------------------------------------------------------
__global__ __launch_bounds__(256) void cvt_f32_bf16(
    const float* __restrict__ in, unsigned short* __restrict__ out, int n4)
{
    for (int i = blockIdx.x * blockDim.x + threadIdx.x; i < n4;
         i += gridDim.x * blockDim.x) {
        float4 v = reinterpret_cast<const float4*>(in)[i];
        ushort4 o;
        o.x = f2bf(v.x); o.y = f2bf(v.y); o.z = f2bf(v.z); o.w = f2bf(v.w);
        reinterpret_cast<ushort4*>(out)[i] = o;
    }
}

// ---------------------------------------------------------------------------
// Kernel 0b: transpose + convert.  in fp32 [R][Cn]  ->  out bf16 [Cn][R].
// ---------------------------------------------------------------------------
__global__ __launch_bounds__(256) void transpose_cvt(
    const float* __restrict__ in, unsigned short* __restrict__ out,
    int R, int Cn)
{
    __shared__ float tile[64][65];
    const int tid = threadIdx.x;
    const int n0  = blockIdx.x * 64;   // input col block
    const int r0  = blockIdx.y * 64;   // input row block

    #pragma unroll
    for (int it = 0; it < 4; ++it) {
        const int idx = tid + it * 256;
        const int lr  = idx >> 4;
        const int lcq = idx & 15;
        float4 v = *reinterpret_cast<const float4*>(
            &in[(size_t)(r0 + lr) * Cn + n0 + lcq * 4]);
        tile[lr][lcq * 4 + 0] = v.x;
        tile[lr][lcq * 4 + 1] = v.y;
        tile[lr][lcq * 4 + 2] = v.z;
        tile[lr][lcq * 4 + 3] = v.w;
    }
    __syncthreads();
    #pragma unroll
    for (int it = 0; it < 4; ++it) {
        const int idx = tid + it * 256;
        const int orow = idx >> 4;
        const int ocq  = idx & 15;
        ushort4 o;
        o.x = f2bf(tile[ocq * 4 + 0][orow]);
        o.y = f2bf(tile[ocq * 4 + 1][orow]);
        o.z = f2bf(tile[ocq * 4 + 2][orow]);
        o.w = f2bf(tile[ocq * 4 + 3][orow]);
        *reinterpret_cast<ushort4*>(&out[(size_t)(n0 + orow) * R + r0 + ocq * 4]) = o;
    }
}

// ---------------------------------------------------------------------------
// Kernel 0c: per-head transpose+convert  V [BH][T][D] f32 -> Vt [BH][D][T] bf16
// Grid: (T/64, D/64, B*H)
// ---------------------------------------------------------------------------
__global__ __launch_bounds__(256) void transpose_cvt_head(
    const float* __restrict__ in, unsigned short* __restrict__ out)
{
    __shared__ float tile[64][65];
    const int tid  = threadIdx.x;
    const int t0   = blockIdx.x * 64;
    const int d0   = blockIdx.y * 64;
    const int head = blockIdx.z;
    const float* ip       = in  + (size_t)head * TT * DD;
    unsigned short* op    = out + (size_t)head * DD * TT;

    #pragma unroll
    for (int it = 0; it < 4; ++it) {
        const int idx = tid + it * 256;
        const int lr  = idx >> 4;          // t offset 0..63
        const int lcq = idx & 15;          // d quad
        float4 v = *reinterpret_cast<const float4*>(
            &ip[(size_t)(t0 + lr) * DD + d0 + lcq * 4]);
        tile[lr][lcq * 4 + 0] = v.x;
        tile[lr][lcq * 4 + 1] = v.y;
        tile[lr][lcq * 4 + 2] = v.z;
        tile[lr][lcq * 4 + 3] = v.w;
    }
    __syncthreads();
    #pragma unroll
    for (int it = 0; it < 4; ++it) {
        const int idx  = tid + it * 256;
        const int orow = idx >> 4;         // d offset 0..63
        const int ocq  = idx & 15;         // t quad
        ushort4 o;
        o.x = f2bf(tile[ocq * 4 + 0][orow]);
        o.y = f2bf(tile[ocq * 4 + 1][orow]);
        o.z = f2bf(tile[ocq * 4 + 2][orow]);
        o.w = f2bf(tile[ocq * 4 + 3][orow]);
        *reinterpret_cast<ushort4*>(&op[(size_t)(d0 + orow) * TT + t0 + ocq * 4]) = o;
    }
}

// ---------------------------------------------------------------------------
// MFMA GEMM:  C[M][N] = A[M][K] * Bt[N][K]^T + bias, K=2048.  (validated r3)
// ---------------------------------------------------------------------------
#define LDP 72   // LDS row pitch in ushorts

template<int MODE>
__global__ __launch_bounds__(256) void gemm_mfma_bf16(
    const unsigned short* __restrict__ A,    // [M][2048] bf16
    const unsigned short* __restrict__ Bt,   // [N][2048] bf16
    const float* __restrict__ bias,          // [N]
    unsigned short* __restrict__ qws,        // MODE 0
    float* __restrict__ kout,                // MODE 0
    float* __restrict__ vout,                // MODE 0
    float* __restrict__ Y)                   // MODE 1
{
    __shared__ unsigned short As[128 * LDP];
    __shared__ unsigned short Bs[128 * LDP];

    const int tid  = threadIdx.x;
    const int bm   = blockIdx.y * 128;
    const int bn   = blockIdx.x * 128;
    const int wave = tid >> 6;
    const int lane = tid & 63;
    const int wr   = wave >> 1;
    const int wc   = wave & 1;
    const int lrow = lane & 15;
    const int lk8  = (lane >> 4) * 8;

    f32x4 acc[4][4];
    #pragma unroll
    for (int i = 0; i < 4; ++i)
        #pragma unroll
        for (int j = 0; j < 4; ++j)
            acc[i][j] = (f32x4){0.f, 0.f, 0.f, 0.f};

    for (int k0 = 0; k0 < 2048; k0 += 64) {
        uint4 ga[4], gb[4];
        #pragma unroll
        for (int it = 0; it < 4; ++it) {
            const int i   = tid + it * 256;
            const int row = i >> 3;
            const int cq  = i & 7;
            ga[it] = *reinterpret_cast<const uint4*>(
                &A[(size_t)(bm + row) * 2048 + k0 + cq * 8]);
            gb[it] = *reinterpret_cast<const uint4*>(
                &Bt[(size_t)(bn + row) * 2048 + k0 + cq * 8]);
        }
        __syncthreads();
        #pragma unroll
        for (int it = 0; it < 4; ++it) {
            const int i   = tid + it * 256;
            const int row = i >> 3;
            const int cq  = i & 7;
            *reinterpret_cast<uint4*>(&As[row * LDP + cq * 8]) = ga[it];
            *reinterpret_cast<uint4*>(&Bs[row * LDP + cq * 8]) = gb[it];
        }
        __syncthreads();

        #pragma unroll
        for (int ks = 0; ks < 2; ++ks) {
            short8 af[4], bf[4];
            #pragma unroll
            for (int mi = 0; mi < 4; ++mi)
                af[mi] = *reinterpret_cast<const short8*>(
                    &As[(wr * 64 + mi * 16 + lrow) * LDP + ks * 32 + lk8]);
            #pragma unroll
            for (int ni = 0; ni < 4; ++ni)
                bf[ni] = *reinterpret_cast<const short8*>(
                    &Bs[(wc * 64 + ni * 16 + lrow) * LDP + ks * 32 + lk8]);
            #pragma unroll
            for (int mi = 0; mi < 4; ++mi)
                #pragma unroll
                for (int ni = 0; ni < 4; ++ni)
                    acc[mi][ni] = __builtin_amdgcn_mfma_f32_16x16x32_bf16(
                        af[mi], bf[ni], acc[mi][ni], 0, 0, 0);
        }
    }

    const int rbase = (lane >> 4) * 4;
    #pragma unroll
    for (int mi = 0; mi < 4; ++mi) {
        #pragma unroll
        for (int ni = 0; ni < 4; ++ni) {
            #pragma unroll
            for (int r = 0; r < 4; ++r) {
                const int grow = bm + wr * 64 + mi * 16 + rbase + r;
                const int gcol = bn + wc * 64 + ni * 16 + lrow;
                const float val = acc[mi][ni][r] + bias[gcol];
                if (MODE == 0) {
                    const int b      = grow >> 11;
                    const int t      = grow & (TT - 1);
                    const int region = gcol >> 11;
                    const int cc     = gcol & (CC - 1);
                    const int h      = cc >> 7;
                    const int d      = cc & (DD - 1);
                    const size_t idx = (((size_t)(b * HH + h)) * TT + t) * DD + d;
                    if (region == 0)      qws[idx]  = f2bf(val);
                    else if (region == 1) kout[idx] = val;
                    else                  vout[idx] = val;
                } else {
                    Y[(size_t)grow * CC + gcol] = val;
                }
            }
        }
    }
}

// ---------------------------------------------------------------------------
// MFMA causal flash attention.
// Grid: (T/64, H, B), 256 threads = 4 waves; wave w owns q-rows w*16..w*16+15.
// K staged fp32->bf16 LDS [64][KDP]  (K rows are 128 wide -> pitch 136!
//   r5 bug: pitch 68 made rows overlap -> absmax 1.54).
// V^T pre-transposed ([B,H,D,T] bf16), staged to LDS [128][KP] (64-wide rows).
// S->LDS fp32 [64][SP]; softmax thread-per-(row,quad); P bf16 -> LDS [64][KP];
// PV MFMA accumulates O fragments (8 d-blocks).
// Fragment maps (validated by r3 GEMM):
//   A/B: lane l = row/col (l&15), k = (l>>4)*8 .. +7 contiguous
//   C/D: col = l&15, row = (l>>4)*4 + reg
// LDS: Ks 17408 + Vts 17408 + Ps 8704 + Ss 17408 + 512 = 61440 B (2 blk/CU)
// ---------------------------------------------------------------------------
#define KDP 136  // Ks pitch (128 d-elements + 8 pad)
#define KP  68   // Vts/Ps pitch (64 keys + 4 pad)
#define SP  68   // fp32 S pitch

__global__ __launch_bounds__(256) void attn_mfma(
    const unsigned short* __restrict__ qws,   // [B,H,T,D] bf16
    const float* __restrict__ kin,            // [B,H,T,D] fp32
    const unsigned short* __restrict__ vt,    // [B,H,D,T] bf16
    unsigned short* __restrict__ aout)        // [B,T,C] bf16
{
    __shared__ unsigned short Ks [64 * KDP];
    __shared__ unsigned short Vts[128 * KP];
    __shared__ unsigned short Ps [64 * KP];
    __shared__ float          Ss [64 * SP];
    __shared__ float          corr_s[64];
    __shared__ float          linv_s[64];

    const int qt   = (TT / 64 - 1) - blockIdx.x;   // heavy tiles first
    const int h    = blockIdx.y;
    const int b    = blockIdx.z;
    const int tid  = threadIdx.x;
    const int wave = tid >> 6;
    const int lane = tid & 63;
    const int lrow = lane & 15;
    const int lk8  = (lane >> 4) * 8;
    const int head = b * HH + h;
    const float scale = 0.08838834764831845f;      // 1/sqrt(128)

    // Q fragments (4 k-steps), rows = qt*64 + wave*16 + lrow
    short8 qf[4];
    {
        const unsigned short* qp =
            qws + ((size_t)head * TT + qt * 64 + wave * 16 + lrow) * DD;
        #pragma unroll
        for (int ks = 0; ks < 4; ++ks)
            qf[ks] = *reinterpret_cast<const short8*>(qp + ks * 32 + lk8);
    }

    f32x4 oacc[8];
    #pragma unroll
    for (int i = 0; i < 8; ++i) oacc[i] = (f32x4){0.f, 0.f, 0.f, 0.f};

    // softmax state: thread handles row srow, key-quad ssub
    const int srow = tid >> 2;
    const int ssub = tid & 3;
    float m = -1e30f, l = 0.f;

    for (int kt = 0; kt <= qt; ++kt) {
        __syncthreads();   // prev PV reads of Vts/Ps done; Ss free
        // --- stage K tile: 64 keys x 128 d, fp32 -> bf16 ---
        {
            const float* kp = kin + ((size_t)head * TT + kt * 64) * DD;
            #pragma unroll
            for (int it = 0; it < 8; ++it) {
                const int i   = tid + it * 256;    // 0..2047 float4s
                const int key = i >> 5;
                const int d0  = (i & 31) * 4;
                float4 v = *reinterpret_cast<const float4*>(kp + (size_t)key * DD + d0);
                ushort4 u;
                u.x = f2bf(v.x); u.y = f2bf(v.y); u.z = f2bf(v.z); u.w = f2bf(v.w);
                *reinterpret_cast<ushort4*>(&Ks[key * KDP + d0]) = u;
            }
        }
        // --- stage Vt tile: 128 d-rows x 64 keys bf16 ---
        {
            const unsigned short* vp = vt + (size_t)head * DD * TT + kt * 64;
            #pragma unroll
            for (int it = 0; it < 8; ++it) {
                const int i  = tid + it * 256;     // 0..2047 ushort4s
                const int d  = i >> 4;
                const int k4 = (i & 15) * 4;
                ushort4 u = *reinterpret_cast<const ushort4*>(vp + (size_t)d * TT + k4);
                *reinterpret_cast<ushort4*>(&Vts[d * KP + k4]) = u;
            }
        }
        __syncthreads();

        // --- QK^T: S fragments ---
        {
            f32x4 sacc[4];
            #pragma unroll
            for (int ni = 0; ni < 4; ++ni) sacc[ni] = (f32x4){0.f, 0.f, 0.f, 0.f};
            #pragma unroll
            for (int ks = 0; ks < 4; ++ks) {
                #pragma unroll
                for (int ni = 0; ni < 4; ++ni) {
                    short8 kf = *reinterpret_cast<const short8*>(
                        &Ks[(ni * 16 + lrow) * KDP + ks * 32 + lk8]);
                    sacc[ni] = __builtin_amdgcn_mfma_f32_16x16x32_bf16(
                        qf[ks], kf, sacc[ni], 0, 0, 0);
                }
            }
            #pragma unroll
            for (int ni = 0; ni < 4; ++ni)
                #pragma unroll
                for (int r = 0; r < 4; ++r)
                    Ss[(wave * 16 + (lane >> 4) * 4 + r) * SP + ni * 16 + lrow] =
                        sacc[ni][r];
        }
        __syncthreads();

        // --- softmax (online) ---
        {
            const int kbase = ssub * 16;
            const bool diag = (kt == qt);
            float sv[16];
            #pragma unroll
            for (int q4 = 0; q4 < 4; ++q4) {
                float4 x = *reinterpret_cast<const float4*>(&Ss[srow * SP + kbase + q4 * 4]);
                sv[q4 * 4 + 0] = x.x; sv[q4 * 4 + 1] = x.y;
                sv[q4 * 4 + 2] = x.z; sv[q4 * 4 + 3] = x.w;
            }
            #pragma unroll
            for (int j = 0; j < 16; ++j) {
                float x = sv[j] * scale;
                if (diag && (kbase + j > srow)) x = -1e30f;
                sv[j] = x;
            }
            float mt = sv[0];
            #pragma unroll
            for (int j = 1; j < 16; ++j) mt = fmaxf(mt, sv[j]);
            mt = fmaxf(mt, __shfl_xor(mt, 1));
            mt = fmaxf(mt, __shfl_xor(mt, 2));
            const float mnew = fmaxf(m, mt);
            const float c    = __expf(m - mnew);
            float ls = 0.f;
            unsigned short pb[16];
            #pragma unroll
            for (int j = 0; j < 16; ++j) {
                const float p = __expf(sv[j] - mnew);
                pb[j] = f2bf(p);
                ls += bf2f(pb[j]);   // denominator from the same rounded P as numerator
            }
            ls += __shfl_xor(ls, 1);
            ls += __shfl_xor(ls, 2);
            l = l * c + ls;
            m = mnew;
            if (ssub == 0) corr_s[srow] = c;
            short8 p0, p1;
            #pragma unroll
            for (int j = 0; j < 8; ++j) { p0[j] = (short)pb[j]; p1[j] = (short)pb[j + 8]; }
            *reinterpret_cast<short8*>(&Ps[srow * KP + kbase])     = p0;
            *reinterpret_cast<short8*>(&Ps[srow * KP + kbase + 8]) = p1;
        }
        __syncthreads();

        // --- PV: rescale O, accumulate P*Vt ---
        {
            float cr[4];
            #pragma unroll
            for (int r = 0; r < 4; ++r)
                cr[r] = corr_s[wave * 16 + (lane >> 4) * 4 + r];
            #pragma unroll
            for (int db = 0; db < 8; ++db)
                #pragma unroll
                for (int r = 0; r < 4; ++r)
                    oacc[db][r] *= cr[r];
            short8 pf[2];
            #pragma unroll
            for (int ksl = 0; ksl < 2; ++ksl)
                pf[ksl] = *reinterpret_cast<const short8*>(
                    &Ps[(wave * 16 + lrow) * KP + ksl * 32 + lk8]);
            #pragma unroll
            for (int db = 0; db < 8; ++db) {
                #pragma unroll
                for (int ksl = 0; ksl < 2; ++ksl) {
                    short8 vf = *reinterpret_cast<const short8*>(
                        &Vts[(db * 16 + lrow) * KP + ksl * 32 + lk8]);
                    oacc[db] = __builtin_amdgcn_mfma_f32_16x16x32_bf16(
                        pf[ksl], vf, oacc[db], 0, 0, 0);
                }
            }
        }
    }

    __syncthreads();
    if (ssub == 0) linv_s[srow] = 1.f / l;
    __syncthreads();

    float li[4];
    #pragma unroll
    for (int r = 0; r < 4; ++r)
        li[r] = linv_s[wave * 16 + (lane >> 4) * 4 + r];
    #pragma unroll
    for (int db = 0; db < 8; ++db) {
        #pragma unroll
        for (int r = 0; r < 4; ++r) {
            const int trow = qt * 64 + wave * 16 + (lane >> 4) * 4 + r;
            aout[((size_t)b * TT + trow) * CC + h * DD + db * 16 + lrow] =
                f2bf(oacc[db][r] * li[r]);
        }
    }
}

// ---------------------------------------------------------------------------
extern "C" void kernel_launch(void* const* d_in, const int* in_sizes, int n_in,
                              void* d_out, int out_size, void* d_ws, size_t ws_size,
                              hipStream_t stream) {
    const float* x    = (const float*)d_in[0];
    // d_in[1] = mask (bool tril) — causal mask hardcoded in attn_mfma
    const float* Wqkv = (const float*)d_in[2];
    const float* bqkv = (const float*)d_in[3];
    const float* Wout = (const float*)d_in[4];
    const float* bout = (const float*)d_in[5];

    float* out  = (float*)d_out;                       // [B,T,C] fp32
    float* kout = out + (size_t)BB * TT * CC;          // [B,H,T,D] fp32
    float* vout = kout + (size_t)BB * TT * CC;         // [B,H,T,D] fp32

    // workspace map (bf16 regions, 16B-aligned). aoutb aliases Xb (dead after gemm1).
    unsigned short* Xb    = (unsigned short*)d_ws;                 // [4096][2048]
    unsigned short* Wqkvt = Xb    + (size_t)4096 * 2048;           // [6144][2048]
    unsigned short* Wott  = Wqkvt + (size_t)6144 * 2048;           // [2048][2048]
    unsigned short* qws   = Wott  + (size_t)2048 * 2048;           // [B,H,T,D]
    unsigned short* vtws  = qws   + (size_t)BB * TT * CC;          // [B,H,D,T]
    unsigned short* aoutb = Xb;                                    // alias

    // 0) conversions
    cvt_f32_bf16<<<2048, 256, 0, stream>>>(x, Xb, (int)((size_t)4096 * 2048 / 4));
    transpose_cvt<<<dim3(N3 / 64, CC / 64), 256, 0, stream>>>(Wqkv, Wqkvt, CC, N3);
    transpose_cvt<<<dim3(CC / 64, CC / 64), 256, 0, stream>>>(Wout, Wott, CC, CC);

    // 1) QKV projection (MFMA) + head scatter
    gemm_mfma_bf16<0><<<dim3(N3 / 128, (BB * TT) / 128), 256, 0, stream>>>(
        Xb, Wqkvt, bqkv, qws, kout, vout, nullptr);

    // 1b) V -> V^T bf16 per head
    transpose_cvt_head<<<dim3(TT / 64, DD / 64, BB * HH), 256, 0, stream>>>(
        vout, vtws);

    // 2) MFMA causal flash attention
    attn_mfma<<<dim3(TT / 64, HH, BB), 256, 0, stream>>>(qws, kout, vtws, aoutb);

    // 3) output projection (MFMA)
    gemm_mfma_bf16<1><<<dim3(CC / 128, (BB * TT) / 128), 256, 0, stream>>>(
        aoutb, Wott, bout, nullptr, nullptr, nullptr, out);
}

// Round 8
// 952.664 us; speedup vs baseline: 6.7145x; 1.0095x over previous
//
#include <hip/hip_runtime.h>
#include <hip/hip_bf16.h>

// Problem constants (reference: B=2, T=2048, DIM=2048, HEADS=16, HEAD_DIM=128)
#define BB   2
#define TT   2048
#define CC   2048
#define HH   16
#define DD   128
#define N3   6144   // 3*DIM

typedef __attribute__((ext_vector_type(8))) short short8;
typedef __attribute__((ext_vector_type(4))) float f32x4;

__device__ inline unsigned short f2bf(float v) {
    __hip_bfloat16 h = __float2bfloat16(v);   // RNE rounding
    return *reinterpret_cast<unsigned short*>(&h);
}
__device__ inline float bf2f(unsigned short u) {
    return __uint_as_float(((unsigned int)u) << 16);
}

// ---------------------------------------------------------------------------
// Kernel 0a: fp32 -> bf16 elementwise (X -> Xb). n4 = float4 count.
// ---------------------------------------------------------------------------
__global__ __launch_bounds__(256) void cvt_f32_bf16(
    const float* __restrict__ in, unsigned short* __restrict__ out, int n4)
{
    for (int i = blockIdx.x * blockDim.x + threadIdx.x; i < n4;
         i += gridDim.x * blockDim.x) {
        float4 v = reinterpret_cast<const float4*>(in)[i];
        ushort4 o;
        o.x = f2bf(v.x); o.y = f2bf(v.y); o.z = f2bf(v.z); o.w = f2bf(v.w);
        reinterpret_cast<ushort4*>(out)[i] = o;
    }
}

// ---------------------------------------------------------------------------
// Kernel 0b: transpose + convert.  in fp32 [R][Cn]  ->  out bf16 [Cn][R].
// ---------------------------------------------------------------------------
__global__ __launch_bounds__(256) void transpose_cvt(
    const float* __restrict__ in, unsigned short* __restrict__ out,
    int R, int Cn)
{
    __shared__ float tile[64][65];
    const int tid = threadIdx.x;
    const int n0  = blockIdx.x * 64;   // input col block
    const int r0  = blockIdx.y * 64;   // input row block

    #pragma unroll
    for (int it = 0; it < 4; ++it) {
        const int idx = tid + it * 256;
        const int lr  = idx >> 4;
        const int lcq = idx & 15;
        float4 v = *reinterpret_cast<const float4*>(
            &in[(size_t)(r0 + lr) * Cn + n0 + lcq * 4]);
        tile[lr][lcq * 4 + 0] = v.x;
        tile[lr][lcq * 4 + 1] = v.y;
        tile[lr][lcq * 4 + 2] = v.z;
        tile[lr][lcq * 4 + 3] = v.w;
    }
    __syncthreads();
    #pragma unroll
    for (int it = 0; it < 4; ++it) {
        const int idx = tid + it * 256;
        const int orow = idx >> 4;
        const int ocq  = idx & 15;
        ushort4 o;
        o.x = f2bf(tile[ocq * 4 + 0][orow]);
        o.y = f2bf(tile[ocq * 4 + 1][orow]);
        o.z = f2bf(tile[ocq * 4 + 2][orow]);
        o.w = f2bf(tile[ocq * 4 + 3][orow]);
        *reinterpret_cast<ushort4*>(&out[(size_t)(n0 + orow) * R + r0 + ocq * 4]) = o;
    }
}

// ---------------------------------------------------------------------------
// Kernel 0c: per-head transpose+convert  V [BH][T][D] f32 -> Vt [BH][D][T] bf16
// Grid: (T/64, D/64, B*H)
// ---------------------------------------------------------------------------
__global__ __launch_bounds__(256) void transpose_cvt_head(
    const float* __restrict__ in, unsigned short* __restrict__ out)
{
    __shared__ float tile[64][65];
    const int tid  = threadIdx.x;
    const int t0   = blockIdx.x * 64;
    const int d0   = blockIdx.y * 64;
    const int head = blockIdx.z;
    const float* ip       = in  + (size_t)head * TT * DD;
    unsigned short* op    = out + (size_t)head * DD * TT;

    #pragma unroll
    for (int it = 0; it < 4; ++it) {
        const int idx = tid + it * 256;
        const int lr  = idx >> 4;          // t offset 0..63
        const int lcq = idx & 15;          // d quad
        float4 v = *reinterpret_cast<const float4*>(
            &ip[(size_t)(t0 + lr) * DD + d0 + lcq * 4]);
        tile[lr][lcq * 4 + 0] = v.x;
        tile[lr][lcq * 4 + 1] = v.y;
        tile[lr][lcq * 4 + 2] = v.z;
        tile[lr][lcq * 4 + 3] = v.w;
    }
    __syncthreads();
    #pragma unroll
    for (int it = 0; it < 4; ++it) {
        const int idx  = tid + it * 256;
        const int orow = idx >> 4;         // d offset 0..63
        const int ocq  = idx & 15;         // t quad
        ushort4 o;
        o.x = f2bf(tile[ocq * 4 + 0][orow]);
        o.y = f2bf(tile[ocq * 4 + 1][orow]);
        o.z = f2bf(tile[ocq * 4 + 2][orow]);
        o.w = f2bf(tile[ocq * 4 + 3][orow]);
        *reinterpret_cast<ushort4*>(&op[(size_t)(d0 + orow) * TT + t0 + ocq * 4]) = o;
    }
}

// ---------------------------------------------------------------------------
// MFMA GEMM:  C[M][N] = A[M][K] * Bt[N][K]^T + bias, K=2048.
// Main loop validated r3/r7. Epilogue r8: LDS-staged coalesced stores
// (r7 scatter epilogue caused 10x HBM write amplification: 823MB vs 84MB).
// Block output region for MODE 0 is 64x128 CONTIGUOUS in [B,H,T,D] since
// bn % 128 == 0 and DD == 128.
// ---------------------------------------------------------------------------
#define LDP 72     // LDS row pitch in ushorts (main loop)
#define EPITCH 130 // fp32 staging pitch (epilogue)

template<int MODE>
__global__ __launch_bounds__(256) void gemm_mfma_bf16(
    const unsigned short* __restrict__ A,    // [M][2048] bf16
    const unsigned short* __restrict__ Bt,   // [N][2048] bf16
    const float* __restrict__ bias,          // [N]
    unsigned short* __restrict__ qws,        // MODE 0
    float* __restrict__ kout,                // MODE 0
    float* __restrict__ vout,                // MODE 0
    float* __restrict__ Y)                   // MODE 1
{
    __shared__ unsigned short smem[2 * 128 * LDP];   // 36864 B
    unsigned short* As = smem;
    unsigned short* Bs = smem + 128 * LDP;

    const int tid  = threadIdx.x;
    const int bm   = blockIdx.y * 128;
    const int bn   = blockIdx.x * 128;
    const int wave = tid >> 6;
    const int lane = tid & 63;
    const int wr   = wave >> 1;
    const int wc   = wave & 1;
    const int lrow = lane & 15;
    const int lk8  = (lane >> 4) * 8;

    f32x4 acc[4][4];
    #pragma unroll
    for (int i = 0; i < 4; ++i)
        #pragma unroll
        for (int j = 0; j < 4; ++j)
            acc[i][j] = (f32x4){0.f, 0.f, 0.f, 0.f};

    for (int k0 = 0; k0 < 2048; k0 += 64) {
        uint4 ga[4], gb[4];
        #pragma unroll
        for (int it = 0; it < 4; ++it) {
            const int i   = tid + it * 256;
            const int row = i >> 3;
            const int cq  = i & 7;
            ga[it] = *reinterpret_cast<const uint4*>(
                &A[(size_t)(bm + row) * 2048 + k0 + cq * 8]);
            gb[it] = *reinterpret_cast<const uint4*>(
                &Bt[(size_t)(bn + row) * 2048 + k0 + cq * 8]);
        }
        __syncthreads();
        #pragma unroll
        for (int it = 0; it < 4; ++it) {
            const int i   = tid + it * 256;
            const int row = i >> 3;
            const int cq  = i & 7;
            *reinterpret_cast<uint4*>(&As[row * LDP + cq * 8]) = ga[it];
            *reinterpret_cast<uint4*>(&Bs[row * LDP + cq * 8]) = gb[it];
        }
        __syncthreads();

        #pragma unroll
        for (int ks = 0; ks < 2; ++ks) {
            short8 af[4], bf[4];
            #pragma unroll
            for (int mi = 0; mi < 4; ++mi)
                af[mi] = *reinterpret_cast<const short8*>(
                    &As[(wr * 64 + mi * 16 + lrow) * LDP + ks * 32 + lk8]);
            #pragma unroll
            for (int ni = 0; ni < 4; ++ni)
                bf[ni] = *reinterpret_cast<const short8*>(
                    &Bs[(wc * 64 + ni * 16 + lrow) * LDP + ks * 32 + lk8]);
            #pragma unroll
            for (int mi = 0; mi < 4; ++mi)
                #pragma unroll
                for (int ni = 0; ni < 4; ++ni)
                    acc[mi][ni] = __builtin_amdgcn_mfma_f32_16x16x32_bf16(
                        af[mi], bf[ni], acc[mi][ni], 0, 0, 0);
        }
    }

    // ---------------- epilogue: LDS-staged coalesced stores ----------------
    const int rbase = (lane >> 4) * 4;
    float* stage = reinterpret_cast<float*>(smem);   // 64 x EPITCH fp32 = 33280 B

    float bv[4];
    #pragma unroll
    for (int ni = 0; ni < 4; ++ni)
        bv[ni] = bias[bn + wc * 64 + ni * 16 + lrow];

    #pragma unroll
    for (int half = 0; half < 2; ++half) {
        __syncthreads();   // LDS free (main loop or prev half's reads done)
        if (wr == half) {
            #pragma unroll
            for (int mi = 0; mi < 4; ++mi)
                #pragma unroll
                for (int ni = 0; ni < 4; ++ni)
                    #pragma unroll
                    for (int r = 0; r < 4; ++r) {
                        const int lr = mi * 16 + rbase + r;        // 0..63
                        const int lc = wc * 64 + ni * 16 + lrow;   // 0..127
                        stage[lr * EPITCH + lc] = acc[mi][ni][r] + bv[ni];
                    }
        }
        __syncthreads();

        const int row0 = bm + half * 64;   // first output row of this half
        if (MODE == 0) {
            const int region = bn >> 11;           // 0=q 1=k 2=v (uniform)
            const int b      = row0 >> 11;
            const int t0     = row0 & (TT - 1);
            const int h      = (bn & (CC - 1)) >> 7;
            const size_t base = (((size_t)(b * HH + h)) * TT + t0) * DD;
            if (region == 0) {
                #pragma unroll
                for (int it = 0; it < 8; ++it) {
                    const int c  = tid + it * 256;       // 0..2047
                    const int lr = c >> 5;
                    const int lc = (c & 31) * 4;
                    float4 v = *reinterpret_cast<const float4*>(&stage[lr * EPITCH + lc]);
                    ushort4 u;
                    u.x = f2bf(v.x); u.y = f2bf(v.y); u.z = f2bf(v.z); u.w = f2bf(v.w);
                    *reinterpret_cast<ushort4*>(&qws[base + (size_t)c * 4]) = u;
                }
            } else {
                float* dst = (region == 1) ? kout : vout;
                #pragma unroll
                for (int it = 0; it < 8; ++it) {
                    const int c  = tid + it * 256;
                    const int lr = c >> 5;
                    const int lc = (c & 31) * 4;
                    float4 v = *reinterpret_cast<const float4*>(&stage[lr * EPITCH + lc]);
                    *reinterpret_cast<float4*>(&dst[base + (size_t)c * 4]) = v;
                }
            }
        } else {
            #pragma unroll
            for (int it = 0; it < 8; ++it) {
                const int c  = tid + it * 256;
                const int lr = c >> 5;
                const int lc = (c & 31) * 4;
                float4 v = *reinterpret_cast<const float4*>(&stage[lr * EPITCH + lc]);
                *reinterpret_cast<float4*>(&Y[(size_t)(row0 + lr) * CC + bn + lc]) = v;
            }
        }
    }
}

// ---------------------------------------------------------------------------
// MFMA causal flash attention.  (validated r7: 961us total, attn < 469us)
// Grid: (T/64, H, B), 256 threads = 4 waves; wave w owns q-rows w*16..w*16+15.
// K staged fp32->bf16 LDS [64][KDP] (pitch 136: K rows are 128 wide).
// V^T pre-transposed ([B,H,D,T] bf16), staged to LDS [128][KP].
// S->LDS fp32 [64][SP]; softmax thread-per-(row,quad); P bf16 -> LDS [64][KP];
// PV MFMA accumulates O fragments (8 d-blocks).
// ---------------------------------------------------------------------------
#define KDP 136  // Ks pitch (128 d-elements + 8 pad)
#define KP  68   // Vts/Ps pitch (64 keys + 4 pad)
#define SP  68   // fp32 S pitch

__global__ __launch_bounds__(256) void attn_mfma(
    const unsigned short* __restrict__ qws,   // [B,H,T,D] bf16
    const float* __restrict__ kin,            // [B,H,T,D] fp32
    const unsigned short* __restrict__ vt,    // [B,H,D,T] bf16
    unsigned short* __restrict__ aout)        // [B,T,C] bf16
{
    __shared__ unsigned short Ks [64 * KDP];
    __shared__ unsigned short Vts[128 * KP];
    __shared__ unsigned short Ps [64 * KP];
    __shared__ float          Ss [64 * SP];
    __shared__ float          corr_s[64];
    __shared__ float          linv_s[64];

    const int qt   = (TT / 64 - 1) - blockIdx.x;   // heavy tiles first
    const int h    = blockIdx.y;
    const int b    = blockIdx.z;
    const int tid  = threadIdx.x;
    const int wave = tid >> 6;
    const int lane = tid & 63;
    const int lrow = lane & 15;
    const int lk8  = (lane >> 4) * 8;
    const int head = b * HH + h;
    const float scale = 0.08838834764831845f;      // 1/sqrt(128)

    // Q fragments (4 k-steps), rows = qt*64 + wave*16 + lrow
    short8 qf[4];
    {
        const unsigned short* qp =
            qws + ((size_t)head * TT + qt * 64 + wave * 16 + lrow) * DD;
        #pragma unroll
        for (int ks = 0; ks < 4; ++ks)
            qf[ks] = *reinterpret_cast<const short8*>(qp + ks * 32 + lk8);
    }

    f32x4 oacc[8];
    #pragma unroll
    for (int i = 0; i < 8; ++i) oacc[i] = (f32x4){0.f, 0.f, 0.f, 0.f};

    // softmax state: thread handles row srow, key-quad ssub
    const int srow = tid >> 2;
    const int ssub = tid & 3;
    float m = -1e30f, l = 0.f;

    for (int kt = 0; kt <= qt; ++kt) {
        __syncthreads();   // prev PV reads of Vts/Ps done; Ss free
        // --- stage K tile: 64 keys x 128 d, fp32 -> bf16 ---
        {
            const float* kp = kin + ((size_t)head * TT + kt * 64) * DD;
            #pragma unroll
            for (int it = 0; it < 8; ++it) {
                const int i   = tid + it * 256;    // 0..2047 float4s
                const int key = i >> 5;
                const int d0  = (i & 31) * 4;
                float4 v = *reinterpret_cast<const float4*>(kp + (size_t)key * DD + d0);
                ushort4 u;
                u.x = f2bf(v.x); u.y = f2bf(v.y); u.z = f2bf(v.z); u.w = f2bf(v.w);
                *reinterpret_cast<ushort4*>(&Ks[key * KDP + d0]) = u;
            }
        }
        // --- stage Vt tile: 128 d-rows x 64 keys bf16 ---
        {
            const unsigned short* vp = vt + (size_t)head * DD * TT + kt * 64;
            #pragma unroll
            for (int it = 0; it < 8; ++it) {
                const int i  = tid + it * 256;     // 0..2047 ushort4s
                const int d  = i >> 4;
                const int k4 = (i & 15) * 4;
                ushort4 u = *reinterpret_cast<const ushort4*>(vp + (size_t)d * TT + k4);
                *reinterpret_cast<ushort4*>(&Vts[d * KP + k4]) = u;
            }
        }
        __syncthreads();

        // --- QK^T: S fragments ---
        {
            f32x4 sacc[4];
            #pragma unroll
            for (int ni = 0; ni < 4; ++ni) sacc[ni] = (f32x4){0.f, 0.f, 0.f, 0.f};
            #pragma unroll
            for (int ks = 0; ks < 4; ++ks) {
                #pragma unroll
                for (int ni = 0; ni < 4; ++ni) {
                    short8 kf = *reinterpret_cast<const short8*>(
                        &Ks[(ni * 16 + lrow) * KDP + ks * 32 + lk8]);
                    sacc[ni] = __builtin_amdgcn_mfma_f32_16x16x32_bf16(
                        qf[ks], kf, sacc[ni], 0, 0, 0);
                }
            }
            #pragma unroll
            for (int ni = 0; ni < 4; ++ni)
                #pragma unroll
                for (int r = 0; r < 4; ++r)
                    Ss[(wave * 16 + (lane >> 4) * 4 + r) * SP + ni * 16 + lrow] =
                        sacc[ni][r];
        }
        __syncthreads();

        // --- softmax (online) ---
        {
            const int kbase = ssub * 16;
            const bool diag = (kt == qt);
            float sv[16];
            #pragma unroll
            for (int q4 = 0; q4 < 4; ++q4) {
                float4 x = *reinterpret_cast<const float4*>(&Ss[srow * SP + kbase + q4 * 4]);
                sv[q4 * 4 + 0] = x.x; sv[q4 * 4 + 1] = x.y;
                sv[q4 * 4 + 2] = x.z; sv[q4 * 4 + 3] = x.w;
            }
            #pragma unroll
            for (int j = 0; j < 16; ++j) {
                float x = sv[j] * scale;
                if (diag && (kbase + j > srow)) x = -1e30f;
                sv[j] = x;
            }
            float mt = sv[0];
            #pragma unroll
            for (int j = 1; j < 16; ++j) mt = fmaxf(mt, sv[j]);
            mt = fmaxf(mt, __shfl_xor(mt, 1));
            mt = fmaxf(mt, __shfl_xor(mt, 2));
            const float mnew = fmaxf(m, mt);
            const float c    = __expf(m - mnew);
            float ls = 0.f;
            unsigned short pb[16];
            #pragma unroll
            for (int j = 0; j < 16; ++j) {
                const float p = __expf(sv[j] - mnew);
                pb[j] = f2bf(p);
                ls += bf2f(pb[j]);   // denominator from the same rounded P as numerator
            }
            ls += __shfl_xor(ls, 1);
            ls += __shfl_xor(ls, 2);
            l = l * c + ls;
            m = mnew;
            if (ssub == 0) corr_s[srow] = c;
            short8 p0, p1;
            #pragma unroll
            for (int j = 0; j < 8; ++j) { p0[j] = (short)pb[j]; p1[j] = (short)pb[j + 8]; }
            *reinterpret_cast<short8*>(&Ps[srow * KP + kbase])     = p0;
            *reinterpret_cast<short8*>(&Ps[srow * KP + kbase + 8]) = p1;
        }
        __syncthreads();

        // --- PV: rescale O, accumulate P*Vt ---
        {
            float cr[4];
            #pragma unroll
            for (int r = 0; r < 4; ++r)
                cr[r] = corr_s[wave * 16 + (lane >> 4) * 4 + r];
            #pragma unroll
            for (int db = 0; db < 8; ++db)
                #pragma unroll
                for (int r = 0; r < 4; ++r)
                    oacc[db][r] *= cr[r];
            short8 pf[2];
            #pragma unroll
            for (int ksl = 0; ksl < 2; ++ksl)
                pf[ksl] = *reinterpret_cast<const short8*>(
                    &Ps[(wave * 16 + lrow) * KP + ksl * 32 + lk8]);
            #pragma unroll
            for (int db = 0; db < 8; ++db) {
                #pragma unroll
                for (int ksl = 0; ksl < 2; ++ksl) {
                    short8 vf = *reinterpret_cast<const short8*>(
                        &Vts[(db * 16 + lrow) * KP + ksl * 32 + lk8]);
                    oacc[db] = __builtin_amdgcn_mfma_f32_16x16x32_bf16(
                        pf[ksl], vf, oacc[db], 0, 0, 0);
                }
            }
        }
    }

    __syncthreads();
    if (ssub == 0) linv_s[srow] = 1.f / l;
    __syncthreads();

    float li[4];
    #pragma unroll
    for (int r = 0; r < 4; ++r)
        li[r] = linv_s[wave * 16 + (lane >> 4) * 4 + r];
    #pragma unroll
    for (int db = 0; db < 8; ++db) {
        #pragma unroll
        for (int r = 0; r < 4; ++r) {
            const int trow = qt * 64 + wave * 16 + (lane >> 4) * 4 + r;
            aout[((size_t)b * TT + trow) * CC + h * DD + db * 16 + lrow] =
                f2bf(oacc[db][r] * li[r]);
        }
    }
}

// ---------------------------------------------------------------------------
extern "C" void kernel_launch(void* const* d_in, const int* in_sizes, int n_in,
                              void* d_out, int out_size, void* d_ws, size_t ws_size,
                              hipStream_t stream) {
    const float* x    = (const float*)d_in[0];
    // d_in[1] = mask (bool tril) — causal mask hardcoded in attn_mfma
    const float* Wqkv = (const float*)d_in[2];
    const float* bqkv = (const float*)d_in[3];
    const float* Wout = (const float*)d_in[4];
    const float* bout = (const float*)d_in[5];

    float* out  = (float*)d_out;                       // [B,T,C] fp32
    float* kout = out + (size_t)BB * TT * CC;          // [B,H,T,D] fp32
    float* vout = kout + (size_t)BB * TT * CC;         // [B,H,T,D] fp32

    // workspace map (bf16 regions, 16B-aligned). aoutb aliases Xb (dead after gemm1).
    unsigned short* Xb    = (unsigned short*)d_ws;                 // [4096][2048]
    unsigned short* Wqkvt = Xb    + (size_t)4096 * 2048;           // [6144][2048]
    unsigned short* Wott  = Wqkvt + (size_t)6144 * 2048;           // [2048][2048]
    unsigned short* qws   = Wott  + (size_t)2048 * 2048;           // [B,H,T,D]
    unsigned short* vtws  = qws   + (size_t)BB * TT * CC;          // [B,H,D,T]
    unsigned short* aoutb = Xb;                                    // alias

    // 0) conversions
    cvt_f32_bf16<<<2048, 256, 0, stream>>>(x, Xb, (int)((size_t)4096 * 2048 / 4));
    transpose_cvt<<<dim3(N3 / 64, CC / 64), 256, 0, stream>>>(Wqkv, Wqkvt, CC, N3);
    transpose_cvt<<<dim3(CC / 64, CC / 64), 256, 0, stream>>>(Wout, Wott, CC, CC);

    // 1) QKV projection (MFMA) + head scatter
    gemm_mfma_bf16<0><<<dim3(N3 / 128, (BB * TT) / 128), 256, 0, stream>>>(
        Xb, Wqkvt, bqkv, qws, kout, vout, nullptr);

    // 1b) V -> V^T bf16 per head
    transpose_cvt_head<<<dim3(TT / 64, DD / 64, BB * HH), 256, 0, stream>>>(
        vout, vtws);

    // 2) MFMA causal flash attention
    attn_mfma<<<dim3(TT / 64, HH, BB), 256, 0, stream>>>(qws, kout, vtws, aoutb);

    // 3) output projection (MFMA)
    gemm_mfma_bf16<1><<<dim3(CC / 128, (BB * TT) / 128), 256, 0, stream>>>(
        aoutb, Wott, bout, nullptr, nullptr, nullptr, out);
}

// Round 12
// 573.528 us; speedup vs baseline: 11.1532x; 1.6611x over previous
//
#include <hip/hip_runtime.h>
#include <hip/hip_bf16.h>

// Problem constants (reference: B=2, T=2048, DIM=2048, HEADS=16, HEAD_DIM=128)
#define BB   2
#define TT   2048
#define CC   2048
#define HH   16
#define DD   128
#define N3   6144   // 3*DIM

typedef __attribute__((ext_vector_type(8))) short short8;
typedef __attribute__((ext_vector_type(4))) float f32x4;

__device__ inline unsigned short f2bf(float v) {
    __hip_bfloat16 h = __float2bfloat16(v);   // RNE rounding
    return *reinterpret_cast<unsigned short*>(&h);
}
__device__ inline float bf2f(unsigned short u) {
    return __uint_as_float(((unsigned int)u) << 16);
}

// async global->LDS, 16B per lane. LDS dest is wave-uniform base + lane*16.
typedef const __attribute__((address_space(1))) unsigned int* gas_u32;
typedef __attribute__((address_space(3))) unsigned int* las_u32;
__device__ __forceinline__ void gload_lds16(const unsigned short* g, unsigned short* l) {
    __builtin_amdgcn_global_load_lds((gas_u32)(const void*)g, (las_u32)(void*)l, 16, 0, 0);
}

// ---------------------------------------------------------------------------
// Kernel 0a: fp32 -> bf16 elementwise (X -> Xb). n4 = float4 count.
// ---------------------------------------------------------------------------
__global__ __launch_bounds__(256) void cvt_f32_bf16(
    const float* __restrict__ in, unsigned short* __restrict__ out, int n4)
{
    for (int i = blockIdx.x * blockDim.x + threadIdx.x; i < n4;
         i += gridDim.x * blockDim.x) {
        float4 v = reinterpret_cast<const float4*>(in)[i];
        ushort4 o;
        o.x = f2bf(v.x); o.y = f2bf(v.y); o.z = f2bf(v.z); o.w = f2bf(v.w);
        reinterpret_cast<ushort4*>(out)[i] = o;
    }
}

// ---------------------------------------------------------------------------
// Kernel 0b: transpose + convert.  in fp32 [R][Cn]  ->  out bf16 [Cn][R].
// ---------------------------------------------------------------------------
__global__ __launch_bounds__(256) void transpose_cvt(
    const float* __restrict__ in, unsigned short* __restrict__ out,
    int R, int Cn)
{
    __shared__ float tile[64][65];
    const int tid = threadIdx.x;
    const int n0  = blockIdx.x * 64;   // input col block
    const int r0  = blockIdx.y * 64;   // input row block

    #pragma unroll
    for (int it = 0; it < 4; ++it) {
        const int idx = tid + it * 256;
        const int lr  = idx >> 4;
        const int lcq = idx & 15;
        float4 v = *reinterpret_cast<const float4*>(
            &in[(size_t)(r0 + lr) * Cn + n0 + lcq * 4]);
        tile[lr][lcq * 4 + 0] = v.x;
        tile[lr][lcq * 4 + 1] = v.y;
        tile[lr][lcq * 4 + 2] = v.z;
        tile[lr][lcq * 4 + 3] = v.w;
    }
    __syncthreads();
    #pragma unroll
    for (int it = 0; it < 4; ++it) {
        const int idx = tid + it * 256;
        const int orow = idx >> 4;
        const int ocq  = idx & 15;
        ushort4 o;
        o.x = f2bf(tile[ocq * 4 + 0][orow]);
        o.y = f2bf(tile[ocq * 4 + 1][orow]);
        o.z = f2bf(tile[ocq * 4 + 2][orow]);
        o.w = f2bf(tile[ocq * 4 + 3][orow]);
        *reinterpret_cast<ushort4*>(&out[(size_t)(n0 + orow) * R + r0 + ocq * 4]) = o;
    }
}

// ---------------------------------------------------------------------------
// Kernel 0c: per-head transpose+convert  V [BH][T][D] f32 -> Vt [BH][D][T] bf16
// Grid: (T/64, D/64, B*H)
// ---------------------------------------------------------------------------
__global__ __launch_bounds__(256) void transpose_cvt_head(
    const float* __restrict__ in, unsigned short* __restrict__ out)
{
    __shared__ float tile[64][65];
    const int tid  = threadIdx.x;
    const int t0   = blockIdx.x * 64;
    const int d0   = blockIdx.y * 64;
    const int head = blockIdx.z;
    const float* ip       = in  + (size_t)head * TT * DD;
    unsigned short* op    = out + (size_t)head * DD * TT;

    #pragma unroll
    for (int it = 0; it < 4; ++it) {
        const int idx = tid + it * 256;
        const int lr  = idx >> 4;          // t offset 0..63
        const int lcq = idx & 15;          // d quad
        float4 v = *reinterpret_cast<const float4*>(
            &ip[(size_t)(t0 + lr) * DD + d0 + lcq * 4]);
        tile[lr][lcq * 4 + 0] = v.x;
        tile[lr][lcq * 4 + 1] = v.y;
        tile[lr][lcq * 4 + 2] = v.z;
        tile[lr][lcq * 4 + 3] = v.w;
    }
    __syncthreads();
    #pragma unroll
    for (int it = 0; it < 4; ++it) {
        const int idx  = tid + it * 256;
        const int orow = idx >> 4;         // d offset 0..63
        const int ocq  = idx & 15;         // t quad
        ushort4 o;
        o.x = f2bf(tile[ocq * 4 + 0][orow]);
        o.y = f2bf(tile[ocq * 4 + 1][orow]);
        o.z = f2bf(tile[ocq * 4 + 2][orow]);
        o.w = f2bf(tile[ocq * 4 + 3][orow]);
        *reinterpret_cast<ushort4*>(&op[(size_t)(d0 + orow) * TT + t0 + ocq * 4]) = o;
    }
}

// ---------------------------------------------------------------------------
// MFMA GEMM:  C[M][N] = A[M][K] * Bt[N][K]^T + bias, K=2048.
// r9: m97 structure — global_load_lds width-16 into LINEAR LDS [128][64]
// (r7/r8 reg-staged path measured 232 TF, MfmaUtil 9%; ladder says gload_lds
// is the big step). XCD-aware swizzle (nwg % 8 == 0, bijective).
// Epilogue: LDS-staged coalesced stores (r8, validated).
// ---------------------------------------------------------------------------
#define EPITCH 130 // fp32 staging pitch (epilogue)

template<int MODE>
__global__ __launch_bounds__(256) void gemm_mfma_bf16(
    const unsigned short* __restrict__ A,    // [M][2048] bf16
    const unsigned short* __restrict__ Bt,   // [N][2048] bf16
    const float* __restrict__ bias,          // [N]
    unsigned short* __restrict__ qws,        // MODE 0
    float* __restrict__ kout,                // MODE 0
    float* __restrict__ vout,                // MODE 0
    float* __restrict__ Y)                   // MODE 1
{
    __shared__ float smem_f[64 * EPITCH];    // 33280 B (>= 32768 main-loop use)
    unsigned short* As = reinterpret_cast<unsigned short*>(smem_f);  // [128][64] linear
    unsigned short* Bs = As + 128 * 64;                              // [128][64] linear

    const int tid  = threadIdx.x;

    // XCD-aware swizzle: tile = (hw%8)*(nwg/8) + hw/8  (bijective; nwg%8==0)
    const int nbx = gridDim.x;
    const int nwg = nbx * gridDim.y;
    const int lin = blockIdx.y * nbx + blockIdx.x;
    const int swz = (lin & 7) * (nwg >> 3) + (lin >> 3);
    const int bm  = (swz / nbx) * 128;
    const int bn  = (swz % nbx) * 128;

    const int wave = tid >> 6;
    const int lane = tid & 63;
    const int wr   = wave >> 1;
    const int wc   = wave & 1;
    const int lrow = lane & 15;
    const int lk8  = (lane >> 4) * 8;

    // staging: chunk c = wave*4+it covers LDS rows c*8..c*8+7 (1024 B), lane
    // writes base+lane*16; global src row = c*8 + (lane>>3), k = (lane&7)*8.
    const int srow = (lane >> 3);         // 0..7
    const int sk   = (lane & 7) * 8;      // k element offset

    f32x4 acc[4][4];
    #pragma unroll
    for (int i = 0; i < 4; ++i)
        #pragma unroll
        for (int j = 0; j < 4; ++j)
            acc[i][j] = (f32x4){0.f, 0.f, 0.f, 0.f};

    for (int k0 = 0; k0 < 2048; k0 += 64) {
        __syncthreads();   // prev-iter LDS reads done
        #pragma unroll
        for (int it = 0; it < 4; ++it) {
            const int c = wave * 4 + it;          // 0..15
            const int row = c * 8 + srow;         // 0..127
            gload_lds16(&A [(size_t)(bm + row) * 2048 + k0 + sk], &As[c * 512]);
            gload_lds16(&Bt[(size_t)(bn + row) * 2048 + k0 + sk], &Bs[c * 512]);
        }
        __syncthreads();   // drains vmcnt -> LDS visible

        #pragma unroll
        for (int ks = 0; ks < 2; ++ks) {
            short8 af[4], bf[4];
            #pragma unroll
            for (int mi = 0; mi < 4; ++mi)
                af[mi] = *reinterpret_cast<const short8*>(
                    &As[(wr * 64 + mi * 16 + lrow) * 64 + ks * 32 + lk8]);
            #pragma unroll
            for (int ni = 0; ni < 4; ++ni)
                bf[ni] = *reinterpret_cast<const short8*>(
                    &Bs[(wc * 64 + ni * 16 + lrow) * 64 + ks * 32 + lk8]);
            #pragma unroll
            for (int mi = 0; mi < 4; ++mi)
                #pragma unroll
                for (int ni = 0; ni < 4; ++ni)
                    acc[mi][ni] = __builtin_amdgcn_mfma_f32_16x16x32_bf16(
                        af[mi], bf[ni], acc[mi][ni], 0, 0, 0);
        }
    }

    // ---------------- epilogue: LDS-staged coalesced stores (r8) ----------
    const int rbase = (lane >> 4) * 4;
    float* stage = smem_f;   // 64 x EPITCH fp32

    float bv[4];
    #pragma unroll
    for (int ni = 0; ni < 4; ++ni)
        bv[ni] = bias[bn + wc * 64 + ni * 16 + lrow];

    #pragma unroll
    for (int half = 0; half < 2; ++half) {
        __syncthreads();   // LDS free (main loop or prev half's reads done)
        if (wr == half) {
            #pragma unroll
            for (int mi = 0; mi < 4; ++mi)
                #pragma unroll
                for (int ni = 0; ni < 4; ++ni)
                    #pragma unroll
                    for (int r = 0; r < 4; ++r) {
                        const int lr = mi * 16 + rbase + r;        // 0..63
                        const int lc = wc * 64 + ni * 16 + lrow;   // 0..127
                        stage[lr * EPITCH + lc] = acc[mi][ni][r] + bv[ni];
                    }
        }
        __syncthreads();

        const int row0 = bm + half * 64;   // first output row of this half
        if (MODE == 0) {
            const int region = bn >> 11;           // 0=q 1=k 2=v (uniform)
            const int b      = row0 >> 11;
            const int t0     = row0 & (TT - 1);
            const int h      = (bn & (CC - 1)) >> 7;
            const size_t base = (((size_t)(b * HH + h)) * TT + t0) * DD;
            if (region == 0) {
                #pragma unroll
                for (int it = 0; it < 8; ++it) {
                    const int c  = tid + it * 256;       // 0..2047
                    const int lr = c >> 5;
                    const int lc = (c & 31) * 4;
                    float4 v = *reinterpret_cast<const float4*>(&stage[lr * EPITCH + lc]);
                    ushort4 u;
                    u.x = f2bf(v.x); u.y = f2bf(v.y); u.z = f2bf(v.z); u.w = f2bf(v.w);
                    *reinterpret_cast<ushort4*>(&qws[base + (size_t)c * 4]) = u;
                }
            } else {
                float* dst = (region == 1) ? kout : vout;
                #pragma unroll
                for (int it = 0; it < 8; ++it) {
                    const int c  = tid + it * 256;
                    const int lr = c >> 5;
                    const int lc = (c & 31) * 4;
                    float4 v = *reinterpret_cast<const float4*>(&stage[lr * EPITCH + lc]);
                    *reinterpret_cast<float4*>(&dst[base + (size_t)c * 4]) = v;
                }
            }
        } else {
            #pragma unroll
            for (int it = 0; it < 8; ++it) {
                const int c  = tid + it * 256;
                const int lr = c >> 5;
                const int lc = (c & 31) * 4;
                float4 v = *reinterpret_cast<const float4*>(&stage[lr * EPITCH + lc]);
                *reinterpret_cast<float4*>(&Y[(size_t)(row0 + lr) * CC + bn + lc]) = v;
            }
        }
    }
}

// ---------------------------------------------------------------------------
// MFMA causal flash attention.  (validated r7/r8; untouched)
// ---------------------------------------------------------------------------
#define KDP 136  // Ks pitch (128 d-elements + 8 pad)
#define KP  68   // Vts/Ps pitch (64 keys + 4 pad)
#define SP  68   // fp32 S pitch

__global__ __launch_bounds__(256) void attn_mfma(
    const unsigned short* __restrict__ qws,   // [B,H,T,D] bf16
    const float* __restrict__ kin,            // [B,H,T,D] fp32
    const unsigned short* __restrict__ vt,    // [B,H,D,T] bf16
    unsigned short* __restrict__ aout)        // [B,T,C] bf16
{
    __shared__ unsigned short Ks [64 * KDP];
    __shared__ unsigned short Vts[128 * KP];
    __shared__ unsigned short Ps [64 * KP];
    __shared__ float          Ss [64 * SP];
    __shared__ float          corr_s[64];
    __shared__ float          linv_s[64];

    const int qt   = (TT / 64 - 1) - blockIdx.x;   // heavy tiles first
    const int h    = blockIdx.y;
    const int b    = blockIdx.z;
    const int tid  = threadIdx.x;
    const int wave = tid >> 6;
    const int lane = tid & 63;
    const int lrow = lane & 15;
    const int lk8  = (lane >> 4) * 8;
    const int head = b * HH + h;
    const float scale = 0.08838834764831845f;      // 1/sqrt(128)

    // Q fragments (4 k-steps), rows = qt*64 + wave*16 + lrow
    short8 qf[4];
    {
        const unsigned short* qp =
            qws + ((size_t)head * TT + qt * 64 + wave * 16 + lrow) * DD;
        #pragma unroll
        for (int ks = 0; ks < 4; ++ks)
            qf[ks] = *reinterpret_cast<const short8*>(qp + ks * 32 + lk8);
    }

    f32x4 oacc[8];
    #pragma unroll
    for (int i = 0; i < 8; ++i) oacc[i] = (f32x4){0.f, 0.f, 0.f, 0.f};

    // softmax state: thread handles row srow, key-quad ssub
    const int srow = tid >> 2;
    const int ssub = tid & 3;
    float m = -1e30f, l = 0.f;

    for (int kt = 0; kt <= qt; ++kt) {
        __syncthreads();   // prev PV reads of Vts/Ps done; Ss free
        // --- stage K tile: 64 keys x 128 d, fp32 -> bf16 ---
        {
            const float* kp = kin + ((size_t)head * TT + kt * 64) * DD;
            #pragma unroll
            for (int it = 0; it < 8; ++it) {
                const int i   = tid + it * 256;    // 0..2047 float4s
                const int key = i >> 5;
                const int d0  = (i & 31) * 4;
                float4 v = *reinterpret_cast<const float4*>(kp + (size_t)key * DD + d0);
                ushort4 u;
                u.x = f2bf(v.x); u.y = f2bf(v.y); u.z = f2bf(v.z); u.w = f2bf(v.w);
                *reinterpret_cast<ushort4*>(&Ks[key * KDP + d0]) = u;
            }
        }
        // --- stage Vt tile: 128 d-rows x 64 keys bf16 ---
        {
            const unsigned short* vp = vt + (size_t)head * DD * TT + kt * 64;
            #pragma unroll
            for (int it = 0; it < 8; ++it) {
                const int i  = tid + it * 256;     // 0..2047 ushort4s
                const int d  = i >> 4;
                const int k4 = (i & 15) * 4;
                ushort4 u = *reinterpret_cast<const ushort4*>(vp + (size_t)d * TT + k4);
                *reinterpret_cast<ushort4*>(&Vts[d * KP + k4]) = u;
            }
        }
        __syncthreads();

        // --- QK^T: S fragments ---
        {
            f32x4 sacc[4];
            #pragma unroll
            for (int ni = 0; ni < 4; ++ni) sacc[ni] = (f32x4){0.f, 0.f, 0.f, 0.f};
            #pragma unroll
            for (int ks = 0; ks < 4; ++ks) {
                #pragma unroll
                for (int ni = 0; ni < 4; ++ni) {
                    short8 kf = *reinterpret_cast<const short8*>(
                        &Ks[(ni * 16 + lrow) * KDP + ks * 32 + lk8]);
                    sacc[ni] = __builtin_amdgcn_mfma_f32_16x16x32_bf16(
                        qf[ks], kf, sacc[ni], 0, 0, 0);
                }
            }
            #pragma unroll
            for (int ni = 0; ni < 4; ++ni)
                #pragma unroll
                for (int r = 0; r < 4; ++r)
                    Ss[(wave * 16 + (lane >> 4) * 4 + r) * SP + ni * 16 + lrow] =
                        sacc[ni][r];
        }
        __syncthreads();

        // --- softmax (online) ---
        {
            const int kbase = ssub * 16;
            const bool diag = (kt == qt);
            float sv[16];
            #pragma unroll
            for (int q4 = 0; q4 < 4; ++q4) {
                float4 x = *reinterpret_cast<const float4*>(&Ss[srow * SP + kbase + q4 * 4]);
                sv[q4 * 4 + 0] = x.x; sv[q4 * 4 + 1] = x.y;
                sv[q4 * 4 + 2] = x.z; sv[q4 * 4 + 3] = x.w;
            }
            #pragma unroll
            for (int j = 0; j < 16; ++j) {
                float x = sv[j] * scale;
                if (diag && (kbase + j > srow)) x = -1e30f;
                sv[j] = x;
            }
            float mt = sv[0];
            #pragma unroll
            for (int j = 1; j < 16; ++j) mt = fmaxf(mt, sv[j]);
            mt = fmaxf(mt, __shfl_xor(mt, 1));
            mt = fmaxf(mt, __shfl_xor(mt, 2));
            const float mnew = fmaxf(m, mt);
            const float c    = __expf(m - mnew);
            float ls = 0.f;
            unsigned short pb[16];
            #pragma unroll
            for (int j = 0; j < 16; ++j) {
                const float p = __expf(sv[j] - mnew);
                pb[j] = f2bf(p);
                ls += bf2f(pb[j]);   // denominator from the same rounded P as numerator
            }
            ls += __shfl_xor(ls, 1);
            ls += __shfl_xor(ls, 2);
            l = l * c + ls;
            m = mnew;
            if (ssub == 0) corr_s[srow] = c;
            short8 p0, p1;
            #pragma unroll
            for (int j = 0; j < 8; ++j) { p0[j] = (short)pb[j]; p1[j] = (short)pb[j + 8]; }
            *reinterpret_cast<short8*>(&Ps[srow * KP + kbase])     = p0;
            *reinterpret_cast<short8*>(&Ps[srow * KP + kbase + 8]) = p1;
        }
        __syncthreads();

        // --- PV: rescale O, accumulate P*Vt ---
        {
            float cr[4];
            #pragma unroll
            for (int r = 0; r < 4; ++r)
                cr[r] = corr_s[wave * 16 + (lane >> 4) * 4 + r];
            #pragma unroll
            for (int db = 0; db < 8; ++db)
                #pragma unroll
                for (int r = 0; r < 4; ++r)
                    oacc[db][r] *= cr[r];
            short8 pf[2];
            #pragma unroll
            for (int ksl = 0; ksl < 2; ++ksl)
                pf[ksl] = *reinterpret_cast<const short8*>(
                    &Ps[(wave * 16 + lrow) * KP + ksl * 32 + lk8]);
            #pragma unroll
            for (int db = 0; db < 8; ++db) {
                #pragma unroll
                for (int ksl = 0; ksl < 2; ++ksl) {
                    short8 vf = *reinterpret_cast<const short8*>(
                        &Vts[(db * 16 + lrow) * KP + ksl * 32 + lk8]);
                    oacc[db] = __builtin_amdgcn_mfma_f32_16x16x32_bf16(
                        pf[ksl], vf, oacc[db], 0, 0, 0);
                }
            }
        }
    }

    __syncthreads();
    if (ssub == 0) linv_s[srow] = 1.f / l;
    __syncthreads();

    float li[4];
    #pragma unroll
    for (int r = 0; r < 4; ++r)
        li[r] = linv_s[wave * 16 + (lane >> 4) * 4 + r];
    #pragma unroll
    for (int db = 0; db < 8; ++db) {
        #pragma unroll
        for (int r = 0; r < 4; ++r) {
            const int trow = qt * 64 + wave * 16 + (lane >> 4) * 4 + r;
            aout[((size_t)b * TT + trow) * CC + h * DD + db * 16 + lrow] =
                f2bf(oacc[db][r] * li[r]);
        }
    }
}

// ---------------------------------------------------------------------------
extern "C" void kernel_launch(void* const* d_in, const int* in_sizes, int n_in,
                              void* d_out, int out_size, void* d_ws, size_t ws_size,
                              hipStream_t stream) {
    const float* x    = (const float*)d_in[0];
    // d_in[1] = mask (bool tril) — causal mask hardcoded in attn_mfma
    const float* Wqkv = (const float*)d_in[2];
    const float* bqkv = (const float*)d_in[3];
    const float* Wout = (const float*)d_in[4];
    const float* bout = (const float*)d_in[5];

    float* out  = (float*)d_out;                       // [B,T,C] fp32
    float* kout = out + (size_t)BB * TT * CC;          // [B,H,T,D] fp32
    float* vout = kout + (size_t)BB * TT * CC;         // [B,H,T,D] fp32

    // workspace map (bf16 regions, 16B-aligned). aoutb aliases Xb (dead after gemm1).
    unsigned short* Xb    = (unsigned short*)d_ws;                 // [4096][2048]
    unsigned short* Wqkvt = Xb    + (size_t)4096 * 2048;           // [6144][2048]
    unsigned short* Wott  = Wqkvt + (size_t)6144 * 2048;           // [2048][2048]
    unsigned short* qws   = Wott  + (size_t)2048 * 2048;           // [B,H,T,D]
    unsigned short* vtws  = qws   + (size_t)BB * TT * CC;          // [B,H,D,T]
    unsigned short* aoutb = Xb;                                    // alias

    // 0) conversions
    cvt_f32_bf16<<<2048, 256, 0, stream>>>(x, Xb, (int)((size_t)4096 * 2048 / 4));
    transpose_cvt<<<dim3(N3 / 64, CC / 64), 256, 0, stream>>>(Wqkv, Wqkvt, CC, N3);
    transpose_cvt<<<dim3(CC / 64, CC / 64), 256, 0, stream>>>(Wout, Wott, CC, CC);

    // 1) QKV projection (MFMA) + head scatter
    gemm_mfma_bf16<0><<<dim3(N3 / 128, (BB * TT) / 128), 256, 0, stream>>>(
        Xb, Wqkvt, bqkv, qws, kout, vout, nullptr);

    // 1b) V -> V^T bf16 per head
    transpose_cvt_head<<<dim3(TT / 64, DD / 64, BB * HH), 256, 0, stream>>>(
        vout, vtws);

    // 2) MFMA causal flash attention
    attn_mfma<<<dim3(TT / 64, HH, BB), 256, 0, stream>>>(qws, kout, vtws, aoutb);

    // 3) output projection (MFMA)
    gemm_mfma_bf16<1><<<dim3(CC / 128, (BB * TT) / 128), 256, 0, stream>>>(
        aoutb, Wott, bout, nullptr, nullptr, nullptr, out);
}